// Round 6
// baseline (264.633 us; speedup 1.0000x reference)
//
#include <hip/hip_runtime.h>
#include <math.h>

typedef float v4f __attribute__((ext_vector_type(4)));

#define CUT  4.0f
#define EPS  1e-11f
#define BOHR 0.5291772105638411f
#define PI_F 3.14159265358979323846f

__device__ __forceinline__ float frcp(float x) { return __builtin_amdgcn_rcpf(x); }

// Recompute pair geometry from the tiny (L1/L2-resident) inputs.
__device__ __forceinline__ void pair_geom(const float* __restrict__ src,
                                          const float* __restrict__ tgt,
                                          unsigned p, unsigned M, unsigned mshift,
                                          float& dist, float& dx, float& dy, float& dz) {
    unsigned n, m;
    if (mshift) { n = p >> mshift; m = p & (M - 1u); }   // M power-of-2 fast path
    else        { n = p / M;       m = p - n * M; }
    float sx = src[3u*n+0], sy = src[3u*n+1], sz = src[3u*n+2];
    float tx = tgt[3u*m+0], ty = tgt[3u*m+1], tz = tgt[3u*m+2];
    dx = tx - sx; dy = ty - sy; dz = tz - sz;
    dist = sqrtf(fmaf(dx, dx, fmaf(dy, dy, dz * dz)));
}

// Stream-specialized: each block owns ONE output array and writes it as a
// single linear stream (fill-like), eliminating per-wave 4-stream interleave.
__global__ __launch_bounds__(256) void deepdft_split_kernel(
    const float* __restrict__ src, const float* __restrict__ tgt,
    float* __restrict__ out, unsigned N, unsigned M, unsigned mshift,
    unsigned bExpEnd, unsigned bDirEnd, unsigned bDistEnd, int expVec)
{
    const unsigned total = N * M;
    const unsigned b = blockIdx.x;
    const unsigned t = threadIdx.x;

    if (b < bExpEnd) {
        // ---- expansion: 80% of bytes, pure linear dwordx4 stream ----
        float* exp_o = out + (size_t)5 * total;
        const unsigned stride = bExpEnd * 256u;
        if (expVec) {
            v4f* gexp = reinterpret_cast<v4f*>(exp_o);
            const unsigned nj = total * 5u;              // float4 elements
            for (unsigned j = b*256u + t; j < nj; j += stride) {
                unsigned p = j / 5u;                     // pair (compiler magic-div)
                unsigned g = j - 5u*p;                   // feature group 0..4
                float dist, dx, dy, dz;
                pair_geom(src, tgt, p, M, mshift, dist, dx, dy, dz);
                float d    = fmaf(dist, BOHR, EPS);
                float invd = frcp(d);
                float x    = (PI_F / CUT) * d;
                float a0 = (float)(4u*g + 1u) * x;
                float a1 = a0 + x, a2 = a1 + x, a3 = a2 + x;
                v4f v;
                v.x = __sinf(a0) * invd;
                v.y = __sinf(a1) * invd;
                v.z = __sinf(a2) * invd;
                v.w = __sinf(a3) * invd;
                gexp[j] = v;                             // 1 KiB/wave, linear
            }
        } else {                                         // alignment fallback
            const unsigned ne = total * 20u;
            for (unsigned e = b*256u + t; e < ne; e += stride) {
                unsigned p = e / 20u;
                unsigned f = e - 20u*p;
                float dist, dx, dy, dz;
                pair_geom(src, tgt, p, M, mshift, dist, dx, dy, dz);
                float d    = fmaf(dist, BOHR, EPS);
                float invd = frcp(d);
                float x    = (PI_F / CUT) * d;
                exp_o[e] = __sinf((float)(f + 1u) * x) * invd;
            }
        }
    } else if (b < bDirEnd) {
        // ---- direction: 12% of bytes, linear dword stream ----
        float* dir_o = out + (size_t)total;
        const unsigned stride = (bDirEnd - bExpEnd) * 256u;
        const unsigned ne = total * 3u;
        for (unsigned e = (b - bExpEnd)*256u + t; e < ne; e += stride) {
            unsigned p = e / 3u;
            unsigned c = e - 3u*p;
            float dist, dx, dy, dz;
            pair_geom(src, tgt, p, M, mshift, dist, dx, dy, dz);
            float inv = frcp(dist + EPS);
            float val = (c == 0u) ? dx : ((c == 1u) ? dy : dz);
            dir_o[e] = val * inv;
        }
    } else if (b < bDistEnd) {
        // ---- dist: 4% of bytes ----
        const unsigned stride = (bDistEnd - bDirEnd) * 256u;
        for (unsigned i = (b - bDirEnd)*256u + t; i < total; i += stride) {
            float dist, dx, dy, dz;
            pair_geom(src, tgt, i, M, mshift, dist, dx, dy, dz);
            out[i] = dist;
        }
    } else {
        // ---- mask: 4% of bytes ----
        float* mask_o = out + (size_t)4 * total;
        const unsigned stride = (gridDim.x - bDistEnd) * 256u;
        for (unsigned i = (b - bDistEnd)*256u + t; i < total; i += stride) {
            float dist, dx, dy, dz;
            pair_geom(src, tgt, i, M, mshift, dist, dx, dy, dz);
            mask_o[i] = (dist < CUT) ? 1.0f : 0.0f;
        }
    }
}

extern "C" void kernel_launch(void* const* d_in, const int* in_sizes, int n_in,
                              void* d_out, int out_size, void* d_ws, size_t ws_size,
                              hipStream_t stream) {
    const float* src = (const float*)d_in[0];   // [1, N, 3] float32
    const float* tgt = (const float*)d_in[1];   // [1, M, 3] float32
    float* out = (float*)d_out;

    unsigned N = (unsigned)(in_sizes[0] / 3);
    unsigned M = (unsigned)(in_sizes[1] / 3);
    unsigned total = N * M;

    unsigned mshift = 0;
    if (M && !(M & (M - 1u))) mshift = (unsigned)__builtin_ctz(M);

    // Block budget split byte-proportionally: exp 80%, dir 12%, dist 4%, mask 4%
    unsigned blocks = 2048u;
    unsigned bExpEnd  = (blocks * 80u) / 100u;             // 1638
    unsigned bDirEnd  = bExpEnd + (blocks * 12u) / 100u;   // 1884
    unsigned bDistEnd = bDirEnd + (blocks * 4u) / 100u;    // 1965
    // mask gets the remainder (83)

    int expVec = (((size_t)20 * total) % 16 == 0);         // v4f alignment of exp seg

    deepdft_split_kernel<<<blocks, 256, 0, stream>>>(
        src, tgt, out, N, M, mshift, bExpEnd, bDirEnd, bDistEnd, expVec);
}

// Round 7
// 242.855 us; speedup vs baseline: 1.0897x; 1.0897x over previous
//
#include <hip/hip_runtime.h>
#include <math.h>

typedef float v4f __attribute__((ext_vector_type(4)));

#define CUT  4.0f
#define EPS  1e-11f
#define BOHR 0.5291772105638411f
#define PI_F 3.14159265358979323846f

__device__ __forceinline__ float frcp(float x) { return __builtin_amdgcn_rcpf(x); }

__device__ __forceinline__ float bperm(unsigned int lane, float v) {
    return __int_as_float(
        __builtin_amdgcn_ds_bpermute((int)(lane << 2), __float_as_int(v)));
}

// geometry for one pair index (inputs are tiny, L1/L2-resident)
__device__ __forceinline__ void pair_geom(const float* __restrict__ src,
                                          const float* __restrict__ tgt,
                                          unsigned p, unsigned M, unsigned mshift,
                                          float& dist, float& dx, float& dy, float& dz) {
    unsigned n, m;
    if (mshift) { n = p >> mshift; m = p & (M - 1u); }
    else        { n = p / M;       m = p - n * M; }
    float sx = src[3u*n+0], sy = src[3u*n+1], sz = src[3u*n+2];
    float tx = tgt[3u*m+0], ty = tgt[3u*m+1], tz = tgt[3u*m+2];
    dx = tx - sx; dy = ty - sy; dz = tz - sz;
    dist = sqrtf(fmaf(dx, dx, fmaf(dy, dy, dz * dz)));
}

// Stream-specialized + wave-cooperative: each wave writes exactly ONE output
// stream; exp/dir waves compute geometry once per pair and redistribute via
// ds_bpermute (round-3 pattern). No LDS tiles, no barriers.
__global__ __launch_bounds__(256) void deepdft_split2_kernel(
    const float* __restrict__ src, const float* __restrict__ tgt,
    float* __restrict__ out, unsigned N, unsigned M, unsigned mshift,
    unsigned bExpEnd, unsigned bDirEnd, unsigned bDistEnd)
{
    const unsigned total  = N * M;
    const unsigned wtiles = (total + 63u) >> 6;
    const unsigned b    = blockIdx.x;
    const unsigned tid  = threadIdx.x;
    const unsigned lane = tid & 63u;

    float* __restrict__ dir_o  = out + (size_t)total;
    float* __restrict__ mask_o = out + (size_t)4 * total;
    float* __restrict__ exp_o  = out + (size_t)5 * total;

    if (b < bExpEnd) {
        // ---- expansion stream (80% of bytes), wave-coop, v4f stores ----
        const unsigned waves  = bExpEnd * 4u;              // 256 thr = 4 waves
        for (unsigned w = (b * 256u + tid) >> 6; w < wtiles; w += waves) {
            const unsigned base = w << 6;
            const unsigned idx  = base + lane;
            const unsigned cidx = (idx < total) ? idx : (total - 1u);
            float dist, dx, dy, dz;
            pair_geom(src, tgt, cidx, M, mshift, dist, dx, dy, dz);
            float d    = fmaf(dist, BOHR, EPS);
            float invd = frcp(d);
            float x    = (PI_F / CUT) * d;

            v4f* gexp = reinterpret_cast<v4f*>(exp_o) + (size_t)5 * base;
            #pragma unroll
            for (int k = 0; k < 5; ++k) {
                unsigned j = lane + 64u * (unsigned)k;     // < 320
                unsigned p = (j * 6554u) >> 15;            // j / 5
                unsigned g = j - 5u * p;                   // j % 5
                float xv = bperm(p, x);
                float iv = bperm(p, invd);
                float a0 = (float)(4u*g + 1u) * xv;
                v4f v;
                v.x = __sinf(a0)            * iv;
                v.y = __sinf(a0 + xv)       * iv;
                v.z = __sinf(a0 + 2.0f*xv)  * iv;
                v.w = __sinf(a0 + 3.0f*xv)  * iv;
                if (base + p < total) gexp[j] = v;         // 1 KiB/wave, one stream
            }
        }
    } else if (b < bDirEnd) {
        // ---- direction stream (12%), wave-coop, dword stores ----
        const unsigned waves = (bDirEnd - bExpEnd) * 4u;
        for (unsigned w = ((b - bExpEnd) * 256u + tid) >> 6; w < wtiles; w += waves) {
            const unsigned base = w << 6;
            const unsigned idx  = base + lane;
            const unsigned cidx = (idx < total) ? idx : (total - 1u);
            float dist, dx, dy, dz;
            pair_geom(src, tgt, cidx, M, mshift, dist, dx, dy, dz);
            float inv = frcp(dist + EPS);
            float ux = dx * inv, uy = dy * inv, uz = dz * inv;

            float* gdir = dir_o + (size_t)3 * base;
            #pragma unroll
            for (int k = 0; k < 3; ++k) {
                unsigned e = lane + 64u * (unsigned)k;     // < 192
                unsigned p = (e * 10923u) >> 15;           // e / 3
                unsigned c = e - 3u * p;                   // e % 3
                float vx = bperm(p, ux);
                float vy = bperm(p, uy);
                float vz = bperm(p, uz);
                float val = (c == 0u) ? vx : ((c == 1u) ? vy : vz);
                if (base + p < total) gdir[e] = val;       // one stream
            }
        }
    } else if (b < bDistEnd) {
        // ---- dist stream (4%) ----
        const unsigned stride = (bDistEnd - bDirEnd) * 256u;
        for (unsigned i = (b - bDirEnd)*256u + tid; i < total; i += stride) {
            float dist, dx, dy, dz;
            pair_geom(src, tgt, i, M, mshift, dist, dx, dy, dz);
            out[i] = dist;
        }
    } else {
        // ---- mask stream (4%) ----
        const unsigned stride = (gridDim.x - bDistEnd) * 256u;
        for (unsigned i = (b - bDistEnd)*256u + tid; i < total; i += stride) {
            float dist, dx, dy, dz;
            pair_geom(src, tgt, i, M, mshift, dist, dx, dy, dz);
            mask_o[i] = (dist < CUT) ? 1.0f : 0.0f;
        }
    }
}

extern "C" void kernel_launch(void* const* d_in, const int* in_sizes, int n_in,
                              void* d_out, int out_size, void* d_ws, size_t ws_size,
                              hipStream_t stream) {
    const float* src = (const float*)d_in[0];   // [1, N, 3] float32
    const float* tgt = (const float*)d_in[1];   // [1, M, 3] float32
    float* out = (float*)d_out;

    unsigned N = (unsigned)(in_sizes[0] / 3);
    unsigned M = (unsigned)(in_sizes[1] / 3);

    unsigned mshift = 0;
    if (M && !(M & (M - 1u))) mshift = (unsigned)__builtin_ctz(M);

    // byte-proportional role split: exp 20/25, dir 3/25, dist 1/25, mask 1/25
    const unsigned blocks   = 2048u;
    const unsigned bExpEnd  = 1638u;
    const unsigned bDirEnd  = 1638u + 246u;   // 1884
    const unsigned bDistEnd = 1884u + 82u;    // 1966, mask gets 82

    deepdft_split2_kernel<<<blocks, 256, 0, stream>>>(
        src, tgt, out, N, M, mshift, bExpEnd, bDirEnd, bDistEnd);
}

// Round 8
// 163.699 us; speedup vs baseline: 1.6166x; 1.4835x over previous
//
#include <hip/hip_runtime.h>
#include <math.h>

typedef float v4f __attribute__((ext_vector_type(4)));

#define CUT  4.0f
#define EPS  1e-11f
#define BOHR 0.5291772105638411f
#define PI_F 3.14159265358979323846f

__device__ __forceinline__ float bperm(unsigned int lane, float v) {
    return __int_as_float(
        __builtin_amdgcn_ds_bpermute((int)(lane << 2), __float_as_int(v)));
}

__global__ __launch_bounds__(256) void deepdft_expansion_kernel(
    const float* __restrict__ src,
    const float* __restrict__ tgt,
    float* __restrict__ out,
    unsigned int N, unsigned int M)
{
    const unsigned int total = N * M;

    float* __restrict__ dist_o = out;
    float* __restrict__ dir_o  = out + (size_t)total;          // [total][3]
    float* __restrict__ mask_o = out + (size_t)4 * total;      // [total]
    float* __restrict__ exp_o  = out + (size_t)5 * total;      // [total][20]

    const unsigned int lane   = threadIdx.x & 63u;
    const unsigned int waves  = (gridDim.x * blockDim.x) >> 6;
    const unsigned int wtiles = (total + 63u) >> 6;
    const unsigned int wid    = (blockIdx.x * blockDim.x + threadIdx.x) >> 6;

    // Chunked (contiguous) wave->tile assignment: each wave owns a run of
    // `chunk` consecutive tiles so each of its 4 output streams is a long
    // sequential DRAM/page run (vs 8192-tile jumps with strided assignment).
    const unsigned int chunk = (wtiles + waves - 1u) / waves;
    const unsigned int tbeg  = wid * chunk;
    const unsigned int tend  = (tbeg + chunk < wtiles) ? (tbeg + chunk) : wtiles;

    for (unsigned int w = tbeg; w < tend; ++w) {
        const unsigned int base = w << 6;
        const unsigned int idx  = base + lane;
        const unsigned int cidx = (idx < total) ? idx : (total - 1u);

        unsigned int n = cidx / M;
        unsigned int m = cidx - n * M;

        float sx = src[3u*n + 0], sy = src[3u*n + 1], sz = src[3u*n + 2];
        float tx = tgt[3u*m + 0], ty = tgt[3u*m + 1], tz = tgt[3u*m + 2];

        float dx = tx - sx, dy = ty - sy, dz = tz - sz;
        float d2   = fmaf(dx, dx, fmaf(dy, dy, dz * dz));
        float dist = sqrtf(d2);
        float inv  = 1.0f / (dist + EPS);

        if (idx < total) {
            dist_o[idx] = dist;                          // coalesced dword
            mask_o[idx] = (dist < CUT) ? 1.0f : 0.0f;    // coalesced dword
        }

        float ux = dx * inv, uy = dy * inv, uz = dz * inv;
        float d    = fmaf(dist, BOHR, EPS);
        float invd = 1.0f / d;
        float x    = (PI_F / CUT) * d;                   // x = pi*d/CUT

        // ---- direction: wave-local transpose [64][3] -> [192] linear ----
        {
            float* gdir = dir_o + (size_t)3 * base;
            #pragma unroll
            for (int k = 0; k < 3; ++k) {
                unsigned int e = lane + 64u * (unsigned)k;    // e < 192
                unsigned int p = (e * 10923u) >> 15;          // e / 3
                unsigned int c = e - 3u * p;                  // e % 3
                float vx = bperm(p, ux);
                float vy = bperm(p, uy);
                float vz = bperm(p, uz);
                float val = (c == 0u) ? vx : ((c == 1u) ? vy : vz);
                if (base + p < total) gdir[e] = val;          // coalesced dword
            }
        }

        // ---- expansion: regenerate sines in output order, v4f stores ----
        {
            v4f* gexp = reinterpret_cast<v4f*>(exp_o) + (size_t)5 * base;
            #pragma unroll
            for (int k = 0; k < 5; ++k) {
                unsigned int j = lane + 64u * (unsigned)k;    // v4 idx < 320
                unsigned int p = (j * 6554u) >> 15;           // j / 5
                unsigned int g = j - 5u * p;                  // j % 5
                float xv = bperm(p, x);
                float iv = bperm(p, invd);
                float n0 = (float)(4u * g + 1u);              // first n of group
                v4f v;
                v.x = __sinf( n0         * xv) * iv;
                v.y = __sinf((n0 + 1.0f) * xv) * iv;
                v.z = __sinf((n0 + 2.0f) * xv) * iv;
                v.w = __sinf((n0 + 3.0f) * xv) * iv;
                if (base + p < total) gexp[j] = v;            // coalesced 1 KiB/wave
            }
        }
    }
}

extern "C" void kernel_launch(void* const* d_in, const int* in_sizes, int n_in,
                              void* d_out, int out_size, void* d_ws, size_t ws_size,
                              hipStream_t stream) {
    const float* src = (const float*)d_in[0];   // [1, N, 3] float32
    const float* tgt = (const float*)d_in[1];   // [1, M, 3] float32
    float* out = (float*)d_out;

    unsigned int N = (unsigned int)(in_sizes[0] / 3);
    unsigned int M = (unsigned int)(in_sizes[1] / 3);
    unsigned int total = N * M;

    const unsigned int block = 256;
    unsigned int wtiles = (total + 63u) >> 6;          // one wave per 64 pairs
    unsigned int blocks = (wtiles + (block / 64) - 1) / (block / 64);
    if (blocks > 2048u) blocks = 2048u;

    deepdft_expansion_kernel<<<blocks, block, 0, stream>>>(src, tgt, out, N, M);
}

// Round 9
// 160.133 us; speedup vs baseline: 1.6526x; 1.0223x over previous
//
#include <hip/hip_runtime.h>
#include <math.h>

typedef float v4f __attribute__((ext_vector_type(4)));

#define CUT  4.0f
#define EPS  1e-11f
#define BOHR 0.5291772105638411f
#define PI_F 3.14159265358979323846f

// 72 KB static LDS: holds src (3N floats) + tgt (3M floats) for N=4096,M=2048
#define LDS_FLOATS 18432

__device__ __forceinline__ float bperm(unsigned int lane, float v) {
    return __int_as_float(
        __builtin_amdgcn_ds_bpermute((int)(lane << 2), __float_as_int(v)));
}

// Staged variant: NO global loads in the steady-state loop -> the compiler
// emits no vmcnt waits in the loop body, so stores are pure fire-and-forget
// and never gate compute (vmcnt is shared by loads AND stores on CDNA).
__global__ __launch_bounds__(256) void deepdft_staged_kernel(
    const float* __restrict__ src,
    const float* __restrict__ tgt,
    float* __restrict__ out,
    unsigned int N, unsigned int M)
{
    __shared__ __align__(16) float lds[LDS_FLOATS];
    float* lsrc = lds;            // 3N floats
    float* ltgt = lds + 3u * N;   // 3M floats

    const unsigned int total = N * M;
    const unsigned int tid   = threadIdx.x;

    // ---- one-time stage: global -> LDS (vectorized when aligned) ----
    {
        const unsigned int ns = 3u * N;
        if ((ns & 3u) == 0u) {
            const unsigned int ns4 = ns >> 2;
            for (unsigned int i = tid; i < ns4; i += blockDim.x)
                ((v4f*)lsrc)[i] = ((const v4f*)src)[i];
        } else {
            for (unsigned int i = tid; i < ns; i += blockDim.x) lsrc[i] = src[i];
        }
        const unsigned int nt = 3u * M;
        if ((ns & 3u) == 0u && (nt & 3u) == 0u) {
            const unsigned int nt4 = nt >> 2;
            for (unsigned int i = tid; i < nt4; i += blockDim.x)
                ((v4f*)ltgt)[i] = ((const v4f*)tgt)[i];
        } else {
            for (unsigned int i = tid; i < nt; i += blockDim.x) ltgt[i] = tgt[i];
        }
    }
    __syncthreads();

    float* __restrict__ dist_o = out;
    float* __restrict__ dir_o  = out + (size_t)total;          // [total][3]
    float* __restrict__ mask_o = out + (size_t)4 * total;      // [total]
    float* __restrict__ exp_o  = out + (size_t)5 * total;      // [total][20]

    const unsigned int lane   = tid & 63u;
    const unsigned int waves  = (gridDim.x * blockDim.x) >> 6;
    const unsigned int wtiles = (total + 63u) >> 6;

    for (unsigned int w = (blockIdx.x * blockDim.x + tid) >> 6;
         w < wtiles; w += waves) {
        const unsigned int base = w << 6;
        const unsigned int idx  = base + lane;
        const unsigned int cidx = (idx < total) ? idx : (total - 1u);

        unsigned int n = cidx / M;
        unsigned int m = cidx - n * M;

        float sx = lsrc[3u*n + 0], sy = lsrc[3u*n + 1], sz = lsrc[3u*n + 2];
        float tx = ltgt[3u*m + 0], ty = ltgt[3u*m + 1], tz = ltgt[3u*m + 2];

        float dx = tx - sx, dy = ty - sy, dz = tz - sz;
        float d2   = fmaf(dx, dx, fmaf(dy, dy, dz * dz));
        float dist = sqrtf(d2);
        float inv  = 1.0f / (dist + EPS);

        if (idx < total) {
            dist_o[idx] = dist;                          // coalesced dword
            mask_o[idx] = (dist < CUT) ? 1.0f : 0.0f;    // coalesced dword
        }

        float ux = dx * inv, uy = dy * inv, uz = dz * inv;
        float d    = fmaf(dist, BOHR, EPS);
        float invd = 1.0f / d;
        float x    = (PI_F / CUT) * d;                   // x = pi*d/CUT

        // ---- direction: wave-local transpose [64][3] -> [192] linear ----
        {
            float* gdir = dir_o + (size_t)3 * base;
            #pragma unroll
            for (int k = 0; k < 3; ++k) {
                unsigned int e = lane + 64u * (unsigned)k;    // e < 192
                unsigned int p = (e * 10923u) >> 15;          // e / 3
                unsigned int c = e - 3u * p;                  // e % 3
                float vx = bperm(p, ux);
                float vy = bperm(p, uy);
                float vz = bperm(p, uz);
                float val = (c == 0u) ? vx : ((c == 1u) ? vy : vz);
                if (base + p < total) gdir[e] = val;          // coalesced dword
            }
        }

        // ---- expansion: regenerate sines in output order, v4f stores ----
        {
            v4f* gexp = reinterpret_cast<v4f*>(exp_o) + (size_t)5 * base;
            #pragma unroll
            for (int k = 0; k < 5; ++k) {
                unsigned int j = lane + 64u * (unsigned)k;    // v4 idx < 320
                unsigned int p = (j * 6554u) >> 15;           // j / 5
                unsigned int g = j - 5u * p;                  // j % 5
                float xv = bperm(p, x);
                float iv = bperm(p, invd);
                float n0 = (float)(4u * g + 1u);              // first n of group
                v4f v;
                v.x = __sinf( n0         * xv) * iv;
                v.y = __sinf((n0 + 1.0f) * xv) * iv;
                v.z = __sinf((n0 + 2.0f) * xv) * iv;
                v.w = __sinf((n0 + 3.0f) * xv) * iv;
                if (base + p < total) gexp[j] = v;            // coalesced 1 KiB/wave
            }
        }
    }
}

// Fallback (round-3 body) for shapes whose inputs don't fit the 72 KB stage.
__global__ __launch_bounds__(256) void deepdft_global_kernel(
    const float* __restrict__ src,
    const float* __restrict__ tgt,
    float* __restrict__ out,
    unsigned int N, unsigned int M)
{
    const unsigned int total = N * M;
    float* __restrict__ dist_o = out;
    float* __restrict__ dir_o  = out + (size_t)total;
    float* __restrict__ mask_o = out + (size_t)4 * total;
    float* __restrict__ exp_o  = out + (size_t)5 * total;

    const unsigned int lane   = threadIdx.x & 63u;
    const unsigned int waves  = (gridDim.x * blockDim.x) >> 6;
    const unsigned int wtiles = (total + 63u) >> 6;

    for (unsigned int w = (blockIdx.x * blockDim.x + threadIdx.x) >> 6;
         w < wtiles; w += waves) {
        const unsigned int base = w << 6;
        const unsigned int idx  = base + lane;
        const unsigned int cidx = (idx < total) ? idx : (total - 1u);
        unsigned int n = cidx / M;
        unsigned int m = cidx - n * M;

        float sx = src[3u*n + 0], sy = src[3u*n + 1], sz = src[3u*n + 2];
        float tx = tgt[3u*m + 0], ty = tgt[3u*m + 1], tz = tgt[3u*m + 2];
        float dx = tx - sx, dy = ty - sy, dz = tz - sz;
        float dist = sqrtf(fmaf(dx, dx, fmaf(dy, dy, dz * dz)));
        float inv  = 1.0f / (dist + EPS);

        if (idx < total) {
            dist_o[idx] = dist;
            mask_o[idx] = (dist < CUT) ? 1.0f : 0.0f;
        }
        float ux = dx * inv, uy = dy * inv, uz = dz * inv;
        float d    = fmaf(dist, BOHR, EPS);
        float invd = 1.0f / d;
        float x    = (PI_F / CUT) * d;

        {
            float* gdir = dir_o + (size_t)3 * base;
            #pragma unroll
            for (int k = 0; k < 3; ++k) {
                unsigned int e = lane + 64u * (unsigned)k;
                unsigned int p = (e * 10923u) >> 15;
                unsigned int c = e - 3u * p;
                float vx = bperm(p, ux);
                float vy = bperm(p, uy);
                float vz = bperm(p, uz);
                float val = (c == 0u) ? vx : ((c == 1u) ? vy : vz);
                if (base + p < total) gdir[e] = val;
            }
        }
        {
            v4f* gexp = reinterpret_cast<v4f*>(exp_o) + (size_t)5 * base;
            #pragma unroll
            for (int k = 0; k < 5; ++k) {
                unsigned int j = lane + 64u * (unsigned)k;
                unsigned int p = (j * 6554u) >> 15;
                unsigned int g = j - 5u * p;
                float xv = bperm(p, x);
                float iv = bperm(p, invd);
                float n0 = (float)(4u * g + 1u);
                v4f v;
                v.x = __sinf( n0         * xv) * iv;
                v.y = __sinf((n0 + 1.0f) * xv) * iv;
                v.z = __sinf((n0 + 2.0f) * xv) * iv;
                v.w = __sinf((n0 + 3.0f) * xv) * iv;
                if (base + p < total) gexp[j] = v;
            }
        }
    }
}

extern "C" void kernel_launch(void* const* d_in, const int* in_sizes, int n_in,
                              void* d_out, int out_size, void* d_ws, size_t ws_size,
                              hipStream_t stream) {
    const float* src = (const float*)d_in[0];   // [1, N, 3] float32
    const float* tgt = (const float*)d_in[1];   // [1, M, 3] float32
    float* out = (float*)d_out;

    unsigned int N = (unsigned int)(in_sizes[0] / 3);
    unsigned int M = (unsigned int)(in_sizes[1] / 3);
    unsigned int total = N * M;

    const unsigned int block = 256;
    unsigned int wtiles = (total + 63u) >> 6;
    unsigned int blocks = (wtiles + (block / 64) - 1) / (block / 64);
    if (blocks > 2048u) blocks = 2048u;

    if (3u * (N + M) <= (unsigned)LDS_FLOATS) {
        deepdft_staged_kernel<<<blocks, block, 0, stream>>>(src, tgt, out, N, M);
    } else {
        deepdft_global_kernel<<<blocks, block, 0, stream>>>(src, tgt, out, N, M);
    }
}